// Round 4
// baseline (1710.239 us; speedup 1.0000x reference)
//
#include <hip/hip_runtime.h>
#include <hip/hip_bf16.h>
#include <math.h>

#define N_NODES 8192
#define IN_DIM  512
#define H_DIM   128
#define KC      1024              // K-chunk per k-block in k_A
#define NKB     (N_NODES / KC)    // 8

typedef __attribute__((ext_vector_type(8))) short bf16x8;
typedef __attribute__((ext_vector_type(4))) float f32x4;

__device__ __forceinline__ float lrelu(float x) { return fmaxf(x, 0.2f * x); }

// monotonic float<->uint mapping for atomicMax on floats (all finite maps > 0)
__device__ __forceinline__ unsigned int f2mono(float x) {
    unsigned int b = __float_as_uint(x);
    return (b & 0x80000000u) ? ~b : (b | 0x80000000u);
}
__device__ __forceinline__ float mono2f(unsigned int u) {
    unsigned int b = (u & 0x80000000u) ? (u ^ 0x80000000u) : ~u;
    return __uint_as_float(b);
}

__device__ __forceinline__ short f2bf(float x) {
    union { __hip_bfloat16 h; short s; } cv;
    cv.h = __float2bfloat16(x);
    return cv.s;
}

// Wh = h @ W_w^T + W_b (f32) ; also WhT = bf16 transpose [H_DIM][N_NODES]
__global__ __launch_bounds__(256) void k_wh(const float* __restrict__ h,
                                            const float* __restrict__ Ww,
                                            const float* __restrict__ Wb,
                                            float* __restrict__ Wh,
                                            __hip_bfloat16* __restrict__ WhT) {
    const int BM = 32, BK = 64;
    __shared__ float hT[BK][BM + 4];
    __shared__ float wT[BK][H_DIM + 4];
    const int tid = threadIdx.x;
    const int w = tid >> 6, lane = tid & 63;
    const int trm = tid >> 5, tcm = tid & 31;
    const int row0 = blockIdx.x * BM;

    float acc[4][4] = {};
    for (int k0 = 0; k0 < IN_DIM; k0 += BK) {
        __syncthreads();
        #pragma unroll
        for (int p = 0; p < 8; ++p) {
            int r = 4 * p + w;
            hT[lane][r] = h[(size_t)(row0 + r) * IN_DIM + k0 + lane];
        }
        #pragma unroll
        for (int p = 0; p < 32; ++p) {
            int c = 4 * p + w;
            wT[lane][c] = Ww[(size_t)c * IN_DIM + k0 + lane];
        }
        __syncthreads();
        #pragma unroll 8
        for (int kk = 0; kk < BK; ++kk) {
            f32x4 a4 = *(const f32x4*)&hT[kk][4 * trm];
            f32x4 b4 = *(const f32x4*)&wT[kk][4 * tcm];
            #pragma unroll
            for (int i = 0; i < 4; ++i)
                #pragma unroll
                for (int j = 0; j < 4; ++j)
                    acc[i][j] = fmaf(a4[i], b4[j], acc[i][j]);
        }
    }
    f32x4 wb4 = *(const f32x4*)&Wb[4 * tcm];
    #pragma unroll
    for (int i = 0; i < 4; ++i) {
        int row = row0 + 4 * trm + i;
        f32x4 v;
        #pragma unroll
        for (int jj = 0; jj < 4; ++jj) v[jj] = acc[i][jj] + wb4[jj];
        *(f32x4*)&Wh[(size_t)row * H_DIM + 4 * tcm] = v;
        #pragma unroll
        for (int jj = 0; jj < 4; ++jj)
            WhT[(size_t)(4 * tcm + jj) * N_NODES + row] = __float2bfloat16(v[jj]);
    }
}

// s_i = Wh_i . a ; global max(s) via mapped atomicMax
__global__ __launch_bounds__(256) void k_s(const float* __restrict__ Wh,
                                           const float* __restrict__ a,
                                           float* __restrict__ s,
                                           unsigned int* __restrict__ smax) {
    const int w = threadIdx.x >> 6, lane = threadIdx.x & 63;
    const int row = blockIdx.x * 4 + w;
    float2 av = *(const float2*)&a[lane * 2];
    float2 wh = *(const float2*)&Wh[(size_t)row * H_DIM + lane * 2];
    float v = wh.x * av.x + wh.y * av.y;
    #pragma unroll
    for (int off = 32; off > 0; off >>= 1) v += __shfl_down(v, off);
    __shared__ float bmax[4];
    if (lane == 0) { s[row] = v; bmax[w] = v; }
    __syncthreads();
    if (threadIdx.x == 0) {
        float m = fmaxf(fmaxf(bmax[0], bmax[1]), fmaxf(bmax[2], bmax[3]));
        atomicMax(smax, f2mono(m));
    }
}

// Streaming MFMA pass over adj: y += EX_chunk @ Whb, denom += rowsum(EX), bitmask.
// Barrier-free, LDS-free. 8 waves: (w&3)=row-group of 16 rows, (w>>2)=col half of 64.
// KC=1024, grid (128,8) = 1024 blocks = 4 blocks/CU = 32 waves/CU for latency hiding.
__global__ __launch_bounds__(512, 8) void k_A(const float* __restrict__ adj,
                                              const __hip_bfloat16* __restrict__ WhT,
                                              const float* __restrict__ s,
                                              const unsigned int* __restrict__ smaxp,
                                              float* __restrict__ denom,
                                              float* __restrict__ y,
                                              unsigned long long* __restrict__ bmask,
                                              int write_mask) {
    const int NTW = N_NODES / 64;  // bmask words per row
    const int tid  = threadIdx.x;
    const int lane = tid & 63;
    const int w    = tid >> 6;
    const int rg   = w & 3;        // row-group
    const int cg   = w >> 2;       // col half
    const int r    = lane & 15;
    const int kq   = lane >> 4;    // k-quarter: k = kq*8 + e
    const int row0 = blockIdx.x * 64;
    const int j0base = blockIdx.y * KC;
    const int rowA = row0 + rg * 16 + r;

    const float smax = mono2f(*smaxp);
    const float si = s[rowA];
    const float mi = lrelu(si + smax);

    f32x4 acc[4] = {{0.f,0.f,0.f,0.f},{0.f,0.f,0.f,0.f},{0.f,0.f,0.f,0.f},{0.f,0.f,0.f,0.f}};
    float dsum = 0.f;

    const float* ap = adj + (size_t)rowA * N_NODES + j0base + kq * 8;
    const float* sp = s + j0base + kq * 8;
    const __hip_bfloat16* bp = WhT + (size_t)(cg * 64 + r) * N_NODES + j0base + kq * 8;

    const int NSTEP = KC / 32;  // 32

    f32x4 ac0 = __builtin_nontemporal_load((const f32x4*)(ap));
    f32x4 ac1 = __builtin_nontemporal_load((const f32x4*)(ap + 4));
    f32x4 sc0 = *(const f32x4*)(sp);
    f32x4 sc1 = *(const f32x4*)(sp + 4);
    bf16x8 bc[4];
    #pragma unroll
    for (int f = 0; f < 4; ++f) bc[f] = *(const bf16x8*)(bp + (size_t)f * 16 * N_NODES);

    unsigned long long pend = 0ull;

    #pragma unroll 2
    for (int t = 0; t < NSTEP; ++t) {
        // prefetch next k-step (uniform branch)
        f32x4 an0, an1, sn0, sn1; bf16x8 bn[4];
        if (t + 1 < NSTEP) {
            const float* ap2 = ap + (size_t)(t + 1) * 32;
            an0 = __builtin_nontemporal_load((const f32x4*)(ap2));
            an1 = __builtin_nontemporal_load((const f32x4*)(ap2 + 4));
            const float* sp2 = sp + (t + 1) * 32;
            sn0 = *(const f32x4*)(sp2);
            sn1 = *(const f32x4*)(sp2 + 4);
            const __hip_bfloat16* bp2 = bp + (t + 1) * 32;
            #pragma unroll
            for (int f = 0; f < 4; ++f) bn[f] = *(const bf16x8*)(bp2 + (size_t)f * 16 * N_NODES);
        }
        // ex for this lane's 8 (row, j) elements, packed into MFMA A-fragment
        float av[8] = {ac0[0], ac0[1], ac0[2], ac0[3], ac1[0], ac1[1], ac1[2], ac1[3]};
        float sv[8] = {sc0[0], sc0[1], sc0[2], sc0[3], sc1[0], sc1[1], sc1[2], sc1[3]};
        bf16x8 afrag;
        unsigned int bits = 0u;
        #pragma unroll
        for (int e = 0; e < 8; ++e) {
            bool nb = (av[e] != 0.f);
            float ex = nb ? __expf(lrelu(si + sv[e]) - mi) : 0.f;
            dsum += ex;
            bits |= nb ? (1u << e) : 0u;
            afrag[e] = f2bf(ex);
        }
        #pragma unroll
        for (int f = 0; f < 4; ++f)
            acc[f] = __builtin_amdgcn_mfma_f32_16x16x32_bf16(afrag, bc[f], acc[f], 0, 0, 0);
        // bitmask: 32 bits/step, combine 2 steps -> 64-bit word (col-half 0 only)
        if (write_mask && cg == 0) {
            unsigned long long w32 = (unsigned long long)bits << (8 * kq);
            if ((t & 1) == 0) {
                pend = w32;
            } else {
                unsigned long long full = pend | (w32 << 32);
                full |= __shfl_xor(full, 16);
                full |= __shfl_xor(full, 32);
                if (lane < 16)
                    bmask[(size_t)(row0 + rg * 16 + lane) * NTW + ((j0base + t * 32) >> 6)] = full;
            }
        }
        ac0 = an0; ac1 = an1; sc0 = sn0; sc1 = sn1;
        #pragma unroll
        for (int f = 0; f < 4; ++f) bc[f] = bn[f];
    }

    // denom partial: sum lanes with same r (kq=0..3), col-half 0 only
    if (cg == 0) {
        float v = dsum;
        v += __shfl_xor(v, 16);
        v += __shfl_xor(v, 32);
        if (lane < 16) atomicAdd(&denom[row0 + rg * 16 + lane], v);
    }
    // y partial: D layout col = c0 + (lane&15), row = (lane>>4)*4 + reg
    #pragma unroll
    for (int f = 0; f < 4; ++f)
        #pragma unroll
        for (int i = 0; i < 4; ++i) {
            int rr = row0 + rg * 16 + kq * 4 + i;
            int cc = cg * 64 + f * 16 + r;
            atomicAdd(&y[(size_t)rr * H_DIM + cc], acc[f][i]);
        }
}

// alpha_ij = ex_ij / denom_i ; reads 8MB bitmask (or adj fallback), writes 268MB nt
__global__ __launch_bounds__(256) void k_B(const unsigned long long* __restrict__ bmask,
                                           const float* __restrict__ adj,
                                           const float* __restrict__ s,
                                           const float* __restrict__ denom,
                                           const unsigned int* __restrict__ smaxp,
                                           float* __restrict__ alpha,
                                           int use_mask) {
    const int NSTEP = N_NODES / 256;  // 32 (each wave covers 256 cols/step as float4)
    const int w = threadIdx.x >> 6, lane = threadIdx.x & 63;
    const int row = blockIdx.x * 4 + w;
    const float smax = mono2f(*smaxp);
    const float si = s[row];
    const float mi = lrelu(si + smax);
    const float d = denom[row];
    const float rd = d > 0.f ? 1.f / d : 0.f;
    float* arow = alpha + (size_t)row * N_NODES;
    if (use_mask) {
        const unsigned long long* mrow = bmask + (size_t)row * (N_NODES / 64);
        #pragma unroll 4
        for (int t = 0; t < NSTEP; ++t) {
            int col = t * 256 + lane * 4;
            unsigned long long mb = mrow[t * 4 + (lane >> 4)];
            int sh = (lane & 15) * 4;
            f32x4 sj = *(const f32x4*)&s[col];
            f32x4 o;
            o[0] = ((mb >> (sh + 0)) & 1ull) ? __expf(lrelu(si + sj[0]) - mi) * rd : 0.f;
            o[1] = ((mb >> (sh + 1)) & 1ull) ? __expf(lrelu(si + sj[1]) - mi) * rd : 0.f;
            o[2] = ((mb >> (sh + 2)) & 1ull) ? __expf(lrelu(si + sj[2]) - mi) * rd : 0.f;
            o[3] = ((mb >> (sh + 3)) & 1ull) ? __expf(lrelu(si + sj[3]) - mi) * rd : 0.f;
            __builtin_nontemporal_store(o, (f32x4*)&arow[col]);
        }
    } else {
        const float* adjrow = adj + (size_t)row * N_NODES;
        #pragma unroll 4
        for (int t = 0; t < NSTEP; ++t) {
            int col = t * 256 + lane * 4;
            f32x4 a4 = __builtin_nontemporal_load((const f32x4*)&adjrow[col]);
            f32x4 sj = *(const f32x4*)&s[col];
            f32x4 o;
            o[0] = (a4[0] != 0.f) ? __expf(lrelu(si + sj[0]) - mi) * rd : 0.f;
            o[1] = (a4[1] != 0.f) ? __expf(lrelu(si + sj[1]) - mi) * rd : 0.f;
            o[2] = (a4[2] != 0.f) ? __expf(lrelu(si + sj[2]) - mi) * rd : 0.f;
            o[3] = (a4[3] != 0.f) ? __expf(lrelu(si + sj[3]) - mi) * rd : 0.f;
            __builtin_nontemporal_store(o, (f32x4*)&arow[col]);
        }
    }
}

// z = sigmoid(y/denom)
__global__ __launch_bounds__(256) void k_z(const float* __restrict__ y,
                                           const float* __restrict__ denom,
                                           float* __restrict__ z) {
    int i = blockIdx.x * 256 + threadIdx.x;
    int row = i >> 7;
    float d = denom[row];
    float rd = d > 0.f ? 1.f / d : 0.f;
    float v = y[i] * rd;
    z[i] = 1.f / (1.f + __expf(-v));
}

extern "C" void kernel_launch(void* const* d_in, const int* in_sizes, int n_in,
                              void* d_out, int out_size, void* d_ws, size_t ws_size,
                              hipStream_t stream) {
    const float* h   = (const float*)d_in[0];
    const float* adj = (const float*)d_in[1];
    const float* Ww  = (const float*)d_in[2];
    const float* Wb  = (const float*)d_in[3];
    const float* a   = (const float*)d_in[4];

    float* z     = (float*)d_out;
    float* alpha = z + (size_t)N_NODES * H_DIM;

    char* ws = (char*)d_ws;
    float* y     = (float*)ws;  ws += sizeof(float) * (size_t)N_NODES * H_DIM;   // 4MB (zeroed)
    float* denom = (float*)ws;  ws += sizeof(float) * N_NODES;                   // 32KB (zeroed)
    unsigned int* smax = (unsigned int*)ws;  ws += 256;                          // (zeroed)
    size_t zero_bytes = (size_t)(ws - (char*)d_ws);
    float* Wh    = (float*)ws;  ws += sizeof(float) * (size_t)N_NODES * H_DIM;   // 4MB
    __hip_bfloat16* WhT = (__hip_bfloat16*)ws;
    ws += sizeof(__hip_bfloat16) * (size_t)N_NODES * H_DIM;                      // 2MB
    float* s     = (float*)ws;  ws += sizeof(float) * N_NODES;                   // 32KB
    unsigned long long* bmask = (unsigned long long*)ws;
    size_t base_need  = (size_t)(ws - (char*)d_ws);
    size_t mask_bytes = (size_t)N_NODES * (N_NODES / 64) * sizeof(unsigned long long);
    int use_mask = (ws_size >= base_need + mask_bytes) ? 1 : 0;

    (void)hipMemsetAsync(d_ws, 0, zero_bytes, stream);
    hipLaunchKernelGGL(k_wh, dim3(N_NODES / 32), dim3(256), 0, stream, h, Ww, Wb, Wh, WhT);
    hipLaunchKernelGGL(k_s,  dim3(N_NODES / 4),  dim3(256), 0, stream, Wh, a, s, smax);
    hipLaunchKernelGGL(k_A,  dim3(N_NODES / 64, NKB), dim3(512), 0, stream,
                       adj, WhT, s, smax, denom, y, bmask, use_mask);
    hipLaunchKernelGGL(k_B,  dim3(N_NODES / 4),  dim3(256), 0, stream,
                       bmask, adj, s, denom, smax, alpha, use_mask);
    hipLaunchKernelGGL(k_z,  dim3((N_NODES * H_DIM) / 256), dim3(256), 0, stream,
                       y, denom, z);
}

// Round 6
// 360.465 us; speedup vs baseline: 4.7445x; 4.7445x over previous
//
#include <hip/hip_runtime.h>
#include <hip/hip_bf16.h>
#include <math.h>

#define N_NODES 8192
#define IN_DIM  512
#define H_DIM   128
#define KC      1024              // K-chunk per k-block in k_A
#define NKB     (N_NODES / KC)    // 8

typedef __attribute__((ext_vector_type(8))) short bf16x8;
typedef __attribute__((ext_vector_type(4))) float f32x4;

__device__ __forceinline__ float lrelu(float x) { return fmaxf(x, 0.2f * x); }

// monotonic float<->uint mapping for atomicMax on floats (all finite maps > 0)
__device__ __forceinline__ unsigned int f2mono(float x) {
    unsigned int b = __float_as_uint(x);
    return (b & 0x80000000u) ? ~b : (b | 0x80000000u);
}
__device__ __forceinline__ float mono2f(unsigned int u) {
    unsigned int b = (u & 0x80000000u) ? (u ^ 0x80000000u) : ~u;
    return __uint_as_float(b);
}

__device__ __forceinline__ short f2bf(float x) {
    union { __hip_bfloat16 h; short s; } cv;
    cv.h = __float2bfloat16(x);
    return cv.s;
}

// Wh = h @ W_w^T + W_b (f32) ; also WhT = bf16 transpose [H_DIM][N_NODES]
__global__ __launch_bounds__(256) void k_wh(const float* __restrict__ h,
                                            const float* __restrict__ Ww,
                                            const float* __restrict__ Wb,
                                            float* __restrict__ Wh,
                                            __hip_bfloat16* __restrict__ WhT) {
    const int BM = 32, BK = 64;
    __shared__ float hT[BK][BM + 4];
    __shared__ float wT[BK][H_DIM + 4];
    const int tid = threadIdx.x;
    const int w = tid >> 6, lane = tid & 63;
    const int trm = tid >> 5, tcm = tid & 31;
    const int row0 = blockIdx.x * BM;

    float acc[4][4] = {};
    for (int k0 = 0; k0 < IN_DIM; k0 += BK) {
        __syncthreads();
        #pragma unroll
        for (int p = 0; p < 8; ++p) {
            int r = 4 * p + w;
            hT[lane][r] = h[(size_t)(row0 + r) * IN_DIM + k0 + lane];
        }
        #pragma unroll
        for (int p = 0; p < 32; ++p) {
            int c = 4 * p + w;
            wT[lane][c] = Ww[(size_t)c * IN_DIM + k0 + lane];
        }
        __syncthreads();
        #pragma unroll 8
        for (int kk = 0; kk < BK; ++kk) {
            f32x4 a4 = *(const f32x4*)&hT[kk][4 * trm];
            f32x4 b4 = *(const f32x4*)&wT[kk][4 * tcm];
            #pragma unroll
            for (int i = 0; i < 4; ++i)
                #pragma unroll
                for (int j = 0; j < 4; ++j)
                    acc[i][j] = fmaf(a4[i], b4[j], acc[i][j]);
        }
    }
    f32x4 wb4 = *(const f32x4*)&Wb[4 * tcm];
    #pragma unroll
    for (int i = 0; i < 4; ++i) {
        int row = row0 + 4 * trm + i;
        f32x4 v;
        #pragma unroll
        for (int jj = 0; jj < 4; ++jj) v[jj] = acc[i][jj] + wb4[jj];
        *(f32x4*)&Wh[(size_t)row * H_DIM + 4 * tcm] = v;
        #pragma unroll
        for (int jj = 0; jj < 4; ++jj)
            WhT[(size_t)(4 * tcm + jj) * N_NODES + row] = __float2bfloat16(v[jj]);
    }
}

// s_i = Wh_i . a ; global max(s) via mapped atomicMax
__global__ __launch_bounds__(256) void k_s(const float* __restrict__ Wh,
                                           const float* __restrict__ a,
                                           float* __restrict__ s,
                                           unsigned int* __restrict__ smax) {
    const int w = threadIdx.x >> 6, lane = threadIdx.x & 63;
    const int row = blockIdx.x * 4 + w;
    float2 av = *(const float2*)&a[lane * 2];
    float2 wh = *(const float2*)&Wh[(size_t)row * H_DIM + lane * 2];
    float v = wh.x * av.x + wh.y * av.y;
    #pragma unroll
    for (int off = 32; off > 0; off >>= 1) v += __shfl_down(v, off);
    __shared__ float bmax[4];
    if (lane == 0) { s[row] = v; bmax[w] = v; }
    __syncthreads();
    if (threadIdx.x == 0) {
        float m = fmaxf(fmaxf(bmax[0], bmax[1]), fmaxf(bmax[2], bmax[3]));
        atomicMax(smax, f2mono(m));
    }
}

// Streaming MFMA pass over adj: y += EX_chunk @ Whb, denom += rowsum(EX), bitmask.
// Barrier-free, LDS-free. 8 waves: (w&3)=row-group of 16 rows, (w>>2)=col half of 64.
// KC=1024 -> grid (128,8): 4 blocks/CU (at <=64 VGPR) = 32 waves/CU for latency hiding.
// NOTE: no __launch_bounds__ min-waves -- (512,8) made the compiler cap VGPR at 32
// and spill ~5GB of scratch traffic (round-4 post-mortem). TLP, not manual prefetch,
// hides latency here, so the body loads directly at use to stay under 64 VGPRs.
__global__ __launch_bounds__(512) void k_A(const float* __restrict__ adj,
                                           const __hip_bfloat16* __restrict__ WhT,
                                           const float* __restrict__ s,
                                           const unsigned int* __restrict__ smaxp,
                                           float* __restrict__ denom,
                                           float* __restrict__ y,
                                           unsigned long long* __restrict__ bmask,
                                           int write_mask) {
    const int NTW = N_NODES / 64;  // bmask words per row
    const int tid  = threadIdx.x;
    const int lane = tid & 63;
    const int w    = tid >> 6;
    const int rg   = w & 3;        // row-group
    const int cg   = w >> 2;       // col half
    const int r    = lane & 15;
    const int kq   = lane >> 4;    // k-quarter: k = kq*8 + e
    const int row0 = blockIdx.x * 64;
    const int j0base = blockIdx.y * KC;
    const int rowA = row0 + rg * 16 + r;

    const float smax = mono2f(*smaxp);
    const float si = s[rowA];
    const float mi = lrelu(si + smax);

    f32x4 acc[4] = {{0.f,0.f,0.f,0.f},{0.f,0.f,0.f,0.f},{0.f,0.f,0.f,0.f},{0.f,0.f,0.f,0.f}};
    float dsum = 0.f;

    const float* ap = adj + (size_t)rowA * N_NODES + j0base + kq * 8;
    const float* sp = s + j0base + kq * 8;
    const __hip_bfloat16* bp = WhT + (size_t)(cg * 64 + r) * N_NODES + j0base + kq * 8;

    const int NSTEP = KC / 32;  // 32

    unsigned long long pend = 0ull;

    #pragma unroll 2
    for (int t = 0; t < NSTEP; ++t) {
        // loads for this k-step (issued up front; TLP across 32 waves/CU hides latency)
        f32x4 ac0 = __builtin_nontemporal_load((const f32x4*)(ap + (size_t)t * 32));
        f32x4 ac1 = __builtin_nontemporal_load((const f32x4*)(ap + (size_t)t * 32 + 4));
        f32x4 sc0 = *(const f32x4*)(sp + t * 32);
        f32x4 sc1 = *(const f32x4*)(sp + t * 32 + 4);
        bf16x8 bc[4];
        #pragma unroll
        for (int f = 0; f < 4; ++f)
            bc[f] = *(const bf16x8*)(bp + (size_t)t * 32 + (size_t)f * 16 * N_NODES);

        // ex for this lane's 8 (row, j) elements, packed into MFMA A-fragment
        float av[8] = {ac0[0], ac0[1], ac0[2], ac0[3], ac1[0], ac1[1], ac1[2], ac1[3]};
        float sv[8] = {sc0[0], sc0[1], sc0[2], sc0[3], sc1[0], sc1[1], sc1[2], sc1[3]};
        bf16x8 afrag;
        unsigned int bits = 0u;
        #pragma unroll
        for (int e = 0; e < 8; ++e) {
            bool nb = (av[e] != 0.f);
            float ex = nb ? __expf(lrelu(si + sv[e]) - mi) : 0.f;
            dsum += ex;
            bits |= nb ? (1u << e) : 0u;
            afrag[e] = f2bf(ex);
        }
        #pragma unroll
        for (int f = 0; f < 4; ++f)
            acc[f] = __builtin_amdgcn_mfma_f32_16x16x32_bf16(afrag, bc[f], acc[f], 0, 0, 0);
        // bitmask: 32 bits/step, combine 2 steps -> 64-bit word (col-half 0 only)
        if (write_mask && cg == 0) {
            unsigned long long w32 = (unsigned long long)bits << (8 * kq);
            if ((t & 1) == 0) {
                pend = w32;
            } else {
                unsigned long long full = pend | (w32 << 32);
                full |= __shfl_xor(full, 16);
                full |= __shfl_xor(full, 32);
                if (lane < 16)
                    bmask[(size_t)(row0 + rg * 16 + lane) * NTW + ((j0base + t * 32) >> 6)] = full;
            }
        }
    }

    // denom partial: sum lanes with same r (kq=0..3), col-half 0 only
    if (cg == 0) {
        float v = dsum;
        v += __shfl_xor(v, 16);
        v += __shfl_xor(v, 32);
        if (lane < 16) atomicAdd(&denom[row0 + rg * 16 + lane], v);
    }
    // y partial: D layout col = c0 + (lane&15), row = (lane>>4)*4 + reg
    #pragma unroll
    for (int f = 0; f < 4; ++f)
        #pragma unroll
        for (int i = 0; i < 4; ++i) {
            int rr = row0 + rg * 16 + kq * 4 + i;
            int cc = cg * 64 + f * 16 + r;
            atomicAdd(&y[(size_t)rr * H_DIM + cc], acc[f][i]);
        }
}

// alpha_ij = ex_ij / denom_i ; reads 8MB bitmask (or adj fallback), writes 268MB nt
__global__ __launch_bounds__(256) void k_B(const unsigned long long* __restrict__ bmask,
                                           const float* __restrict__ adj,
                                           const float* __restrict__ s,
                                           const float* __restrict__ denom,
                                           const unsigned int* __restrict__ smaxp,
                                           float* __restrict__ alpha,
                                           int use_mask) {
    const int NSTEP = N_NODES / 256;  // 32 (each wave covers 256 cols/step as float4)
    const int w = threadIdx.x >> 6, lane = threadIdx.x & 63;
    const int row = blockIdx.x * 4 + w;
    const float smax = mono2f(*smaxp);
    const float si = s[row];
    const float mi = lrelu(si + smax);
    const float d = denom[row];
    const float rd = d > 0.f ? 1.f / d : 0.f;
    float* arow = alpha + (size_t)row * N_NODES;
    if (use_mask) {
        const unsigned long long* mrow = bmask + (size_t)row * (N_NODES / 64);
        #pragma unroll 4
        for (int t = 0; t < NSTEP; ++t) {
            int col = t * 256 + lane * 4;
            unsigned long long mb = mrow[t * 4 + (lane >> 4)];
            int sh = (lane & 15) * 4;
            f32x4 sj = *(const f32x4*)&s[col];
            f32x4 o;
            o[0] = ((mb >> (sh + 0)) & 1ull) ? __expf(lrelu(si + sj[0]) - mi) * rd : 0.f;
            o[1] = ((mb >> (sh + 1)) & 1ull) ? __expf(lrelu(si + sj[1]) - mi) * rd : 0.f;
            o[2] = ((mb >> (sh + 2)) & 1ull) ? __expf(lrelu(si + sj[2]) - mi) * rd : 0.f;
            o[3] = ((mb >> (sh + 3)) & 1ull) ? __expf(lrelu(si + sj[3]) - mi) * rd : 0.f;
            __builtin_nontemporal_store(o, (f32x4*)&arow[col]);
        }
    } else {
        const float* adjrow = adj + (size_t)row * N_NODES;
        #pragma unroll 4
        for (int t = 0; t < NSTEP; ++t) {
            int col = t * 256 + lane * 4;
            f32x4 a4 = __builtin_nontemporal_load((const f32x4*)&adjrow[col]);
            f32x4 sj = *(const f32x4*)&s[col];
            f32x4 o;
            o[0] = (a4[0] != 0.f) ? __expf(lrelu(si + sj[0]) - mi) * rd : 0.f;
            o[1] = (a4[1] != 0.f) ? __expf(lrelu(si + sj[1]) - mi) * rd : 0.f;
            o[2] = (a4[2] != 0.f) ? __expf(lrelu(si + sj[2]) - mi) * rd : 0.f;
            o[3] = (a4[3] != 0.f) ? __expf(lrelu(si + sj[3]) - mi) * rd : 0.f;
            __builtin_nontemporal_store(o, (f32x4*)&arow[col]);
        }
    }
}

// z = sigmoid(y/denom)
__global__ __launch_bounds__(256) void k_z(const float* __restrict__ y,
                                           const float* __restrict__ denom,
                                           float* __restrict__ z) {
    int i = blockIdx.x * 256 + threadIdx.x;
    int row = i >> 7;
    float d = denom[row];
    float rd = d > 0.f ? 1.f / d : 0.f;
    float v = y[i] * rd;
    z[i] = 1.f / (1.f + __expf(-v));
}

extern "C" void kernel_launch(void* const* d_in, const int* in_sizes, int n_in,
                              void* d_out, int out_size, void* d_ws, size_t ws_size,
                              hipStream_t stream) {
    const float* h   = (const float*)d_in[0];
    const float* adj = (const float*)d_in[1];
    const float* Ww  = (const float*)d_in[2];
    const float* Wb  = (const float*)d_in[3];
    const float* a   = (const float*)d_in[4];

    float* z     = (float*)d_out;
    float* alpha = z + (size_t)N_NODES * H_DIM;

    char* ws = (char*)d_ws;
    float* y     = (float*)ws;  ws += sizeof(float) * (size_t)N_NODES * H_DIM;   // 4MB (zeroed)
    float* denom = (float*)ws;  ws += sizeof(float) * N_NODES;                   // 32KB (zeroed)
    unsigned int* smax = (unsigned int*)ws;  ws += 256;                          // (zeroed)
    size_t zero_bytes = (size_t)(ws - (char*)d_ws);
    float* Wh    = (float*)ws;  ws += sizeof(float) * (size_t)N_NODES * H_DIM;   // 4MB
    __hip_bfloat16* WhT = (__hip_bfloat16*)ws;
    ws += sizeof(__hip_bfloat16) * (size_t)N_NODES * H_DIM;                      // 2MB
    float* s     = (float*)ws;  ws += sizeof(float) * N_NODES;                   // 32KB
    unsigned long long* bmask = (unsigned long long*)ws;
    size_t base_need  = (size_t)(ws - (char*)d_ws);
    size_t mask_bytes = (size_t)N_NODES * (N_NODES / 64) * sizeof(unsigned long long);
    int use_mask = (ws_size >= base_need + mask_bytes) ? 1 : 0;

    (void)hipMemsetAsync(d_ws, 0, zero_bytes, stream);
    hipLaunchKernelGGL(k_wh, dim3(N_NODES / 32), dim3(256), 0, stream, h, Ww, Wb, Wh, WhT);
    hipLaunchKernelGGL(k_s,  dim3(N_NODES / 4),  dim3(256), 0, stream, Wh, a, s, smax);
    hipLaunchKernelGGL(k_A,  dim3(N_NODES / 64, NKB), dim3(512), 0, stream,
                       adj, WhT, s, smax, denom, y, bmask, use_mask);
    hipLaunchKernelGGL(k_B,  dim3(N_NODES / 4),  dim3(256), 0, stream,
                       bmask, adj, s, denom, smax, alpha, use_mask);
    hipLaunchKernelGGL(k_z,  dim3((N_NODES * H_DIM) / 256), dim3(256), 0, stream,
                       y, denom, z);
}

// Round 7
// 290.984 us; speedup vs baseline: 5.8774x; 1.2388x over previous
//
#include <hip/hip_runtime.h>
#include <hip/hip_bf16.h>
#include <math.h>

#define N_NODES 8192
#define IN_DIM  512
#define H_DIM   128
#define KC      1024              // K-chunk per k-block in k_A
#define NKB     (N_NODES / KC)    // 8

typedef __attribute__((ext_vector_type(8))) short bf16x8;
typedef __attribute__((ext_vector_type(4))) float f32x4;

__device__ __forceinline__ float lrelu(float x) { return fmaxf(x, 0.2f * x); }

// monotonic float<->uint mapping for atomicMax on floats (all finite maps > 0)
__device__ __forceinline__ unsigned int f2mono(float x) {
    unsigned int b = __float_as_uint(x);
    return (b & 0x80000000u) ? ~b : (b | 0x80000000u);
}
__device__ __forceinline__ float mono2f(unsigned int u) {
    unsigned int b = (u & 0x80000000u) ? (u ^ 0x80000000u) : ~u;
    return __uint_as_float(b);
}

__device__ __forceinline__ short f2bf(float x) {
    union { __hip_bfloat16 h; short s; } cv;
    cv.h = __float2bfloat16(x);
    return cv.s;
}

// Wh = h @ W_w^T + W_b (f32) ; also WhT = bf16 transpose [H_DIM][N_NODES]
__global__ __launch_bounds__(256) void k_wh(const float* __restrict__ h,
                                            const float* __restrict__ Ww,
                                            const float* __restrict__ Wb,
                                            float* __restrict__ Wh,
                                            __hip_bfloat16* __restrict__ WhT) {
    const int BM = 32, BK = 64;
    __shared__ float hT[BK][BM + 4];
    __shared__ float wT[BK][H_DIM + 4];
    const int tid = threadIdx.x;
    const int w = tid >> 6, lane = tid & 63;
    const int trm = tid >> 5, tcm = tid & 31;
    const int row0 = blockIdx.x * BM;

    float acc[4][4] = {};
    for (int k0 = 0; k0 < IN_DIM; k0 += BK) {
        __syncthreads();
        #pragma unroll
        for (int p = 0; p < 8; ++p) {
            int r = 4 * p + w;
            hT[lane][r] = h[(size_t)(row0 + r) * IN_DIM + k0 + lane];
        }
        #pragma unroll
        for (int p = 0; p < 32; ++p) {
            int c = 4 * p + w;
            wT[lane][c] = Ww[(size_t)c * IN_DIM + k0 + lane];
        }
        __syncthreads();
        #pragma unroll 8
        for (int kk = 0; kk < BK; ++kk) {
            f32x4 a4 = *(const f32x4*)&hT[kk][4 * trm];
            f32x4 b4 = *(const f32x4*)&wT[kk][4 * tcm];
            #pragma unroll
            for (int i = 0; i < 4; ++i)
                #pragma unroll
                for (int j = 0; j < 4; ++j)
                    acc[i][j] = fmaf(a4[i], b4[j], acc[i][j]);
        }
    }
    f32x4 wb4 = *(const f32x4*)&Wb[4 * tcm];
    #pragma unroll
    for (int i = 0; i < 4; ++i) {
        int row = row0 + 4 * trm + i;
        f32x4 v;
        #pragma unroll
        for (int jj = 0; jj < 4; ++jj) v[jj] = acc[i][jj] + wb4[jj];
        *(f32x4*)&Wh[(size_t)row * H_DIM + 4 * tcm] = v;
        #pragma unroll
        for (int jj = 0; jj < 4; ++jj)
            WhT[(size_t)(4 * tcm + jj) * N_NODES + row] = __float2bfloat16(v[jj]);
    }
}

// s_i = Wh_i . a ; global max(s) via mapped atomicMax
__global__ __launch_bounds__(256) void k_s(const float* __restrict__ Wh,
                                           const float* __restrict__ a,
                                           float* __restrict__ s,
                                           unsigned int* __restrict__ smax) {
    const int w = threadIdx.x >> 6, lane = threadIdx.x & 63;
    const int row = blockIdx.x * 4 + w;
    float2 av = *(const float2*)&a[lane * 2];
    float2 wh = *(const float2*)&Wh[(size_t)row * H_DIM + lane * 2];
    float v = wh.x * av.x + wh.y * av.y;
    #pragma unroll
    for (int off = 32; off > 0; off >>= 1) v += __shfl_down(v, off);
    __shared__ float bmax[4];
    if (lane == 0) { s[row] = v; bmax[w] = v; }
    __syncthreads();
    if (threadIdx.x == 0) {
        float m = fmaxf(fmaxf(bmax[0], bmax[1]), fmaxf(bmax[2], bmax[3]));
        atomicMax(smax, f2mono(m));
    }
}

// Streaming MFMA pass over adj: y += EX_chunk @ Whb, denom += rowsum(EX), bitmask.
// Round-6 post-mortem: per-fragment adj loads (16 rows x 64B at 32KB stride per
// instruction) capped delivered HBM at ~1.25 TB/s. Fix: cooperative CONTIGUOUS
// staging -- each wave instruction reads 1KB as 2x512B row segments; adj!=0 is
// compressed to byte masks in LDS (8KB/tile, XOR-swizzled slots); fragments then
// read 8 mask bytes via one ds_read_b64. MFMA/bitmask/denom paths unchanged.
__global__ __launch_bounds__(512) void k_A(const float* __restrict__ adj,
                                           const __hip_bfloat16* __restrict__ WhT,
                                           const float* __restrict__ s,
                                           const unsigned int* __restrict__ smaxp,
                                           float* __restrict__ denom,
                                           float* __restrict__ y,
                                           unsigned long long* __restrict__ bmask,
                                           int write_mask) {
    __shared__ unsigned char msk[64 * 128];   // byte mask tile, slot-swizzled
    const int NTW = N_NODES / 64;  // bmask words per row
    const int tid  = threadIdx.x;
    const int lane = tid & 63;
    const int w    = tid >> 6;
    const int rg   = w & 3;        // row-group
    const int cg   = w >> 2;       // col half
    const int r16  = lane & 15;
    const int kq   = lane >> 4;    // k-quarter: k = kq*8 + e
    const int row0 = blockIdx.x * 64;
    const int j0base = blockIdx.y * KC;
    const int rowA = row0 + rg * 16 + r16;

    const float smax = mono2f(*smaxp);
    const float si = s[rowA];
    const float mi = lrelu(si + smax);

    f32x4 acc[4] = {{0.f,0.f,0.f,0.f},{0.f,0.f,0.f,0.f},{0.f,0.f,0.f,0.f},{0.f,0.f,0.f,0.f}};
    float dsum = 0.f;

    const float* sp = s + j0base + kq * 8;
    const __hip_bfloat16* bp = WhT + (size_t)(cg * 64 + r16) * N_NODES + j0base + kq * 8;

    unsigned long long pend = 0ull;

    const int NBIG = KC / 128;  // 8 big-steps of 128 cols
    for (int bs = 0; bs < NBIG; ++bs) {
        const int j0 = j0base + bs * 128;

        // ---- stage: contiguous loads (1KB per wave instr = 2x512B segments) ----
        const int cS = (lane & 31) * 4;        // col of this lane's 4 floats
        const int rOff = (lane >> 5);
        unsigned int mword[4];
        #pragma unroll
        for (int p = 0; p < 4; ++p) {
            int ci = w * 4 + p;
            int rS = 2 * ci + rOff;
            f32x4 a4 = __builtin_nontemporal_load(
                (const f32x4*)(adj + (size_t)(row0 + rS) * N_NODES + j0 + cS));
            unsigned int mwd = 0u;
            mwd |= (a4[0] != 0.f) ? 0x00000001u : 0u;
            mwd |= (a4[1] != 0.f) ? 0x00000100u : 0u;
            mwd |= (a4[2] != 0.f) ? 0x00010000u : 0u;
            mwd |= (a4[3] != 0.f) ? 0x01000000u : 0u;
            mword[p] = mwd;
        }
        __syncthreads();   // previous tile fully consumed
        #pragma unroll
        for (int p = 0; p < 4; ++p) {
            int ci = w * 4 + p;
            int rS = 2 * ci + rOff;
            int slot = ((cS >> 3) ^ (rS & 15));
            *(unsigned int*)&msk[rS * 128 + (slot << 3) + (cS & 7)] = mword[p];
        }
        __syncthreads();   // tile visible to all waves

        // ---- consume: 4 MFMA substeps of 32 cols ----
        #pragma unroll
        for (int sub = 0; sub < 4; ++sub) {
            const int ts = bs * 4 + sub;          // 0..31, same as old step index
            const int rT = rg * 16 + r16;
            const int slotR = (sub * 4 + kq) ^ r16;
            unsigned long long m8 =
                *(const unsigned long long*)&msk[rT * 128 + (slotR << 3)];

            f32x4 sc0 = *(const f32x4*)(sp + ts * 32);
            f32x4 sc1 = *(const f32x4*)(sp + ts * 32 + 4);
            bf16x8 bc[4];
            #pragma unroll
            for (int f = 0; f < 4; ++f)
                bc[f] = *(const bf16x8*)(bp + (size_t)ts * 32 + (size_t)f * 16 * N_NODES);

            float sv[8] = {sc0[0], sc0[1], sc0[2], sc0[3], sc1[0], sc1[1], sc1[2], sc1[3]};
            bf16x8 afrag;
            unsigned int bits = 0u;
            #pragma unroll
            for (int e = 0; e < 8; ++e) {
                bool nb = ((m8 >> (8 * e)) & 0xffull) != 0ull;
                float ex = nb ? __expf(lrelu(si + sv[e]) - mi) : 0.f;
                dsum += ex;
                bits |= nb ? (1u << e) : 0u;
                afrag[e] = f2bf(ex);
            }
            #pragma unroll
            for (int f = 0; f < 4; ++f)
                acc[f] = __builtin_amdgcn_mfma_f32_16x16x32_bf16(afrag, bc[f], acc[f], 0, 0, 0);

            // bitmask: 32 bits/step, combine 2 steps -> 64-bit word (col-half 0 only)
            if (write_mask && cg == 0) {
                unsigned long long w32 = (unsigned long long)bits << (8 * kq);
                if ((ts & 1) == 0) {
                    pend = w32;
                } else {
                    unsigned long long full = pend | (w32 << 32);
                    full |= __shfl_xor(full, 16);
                    full |= __shfl_xor(full, 32);
                    if (lane < 16)
                        bmask[(size_t)(row0 + rg * 16 + lane) * NTW + ((j0base + ts * 32) >> 6)] = full;
                }
            }
        }
    }

    // denom partial: sum lanes with same r (kq=0..3), col-half 0 only
    if (cg == 0) {
        float v = dsum;
        v += __shfl_xor(v, 16);
        v += __shfl_xor(v, 32);
        if (lane < 16) atomicAdd(&denom[row0 + rg * 16 + lane], v);
    }
    // y partial: D layout col = c0 + (lane&15), row = (lane>>4)*4 + reg
    #pragma unroll
    for (int f = 0; f < 4; ++f)
        #pragma unroll
        for (int i = 0; i < 4; ++i) {
            int rr = row0 + rg * 16 + kq * 4 + i;
            int cc = cg * 64 + f * 16 + r16;
            atomicAdd(&y[(size_t)rr * H_DIM + cc], acc[f][i]);
        }
}

// alpha_ij = ex_ij / denom_i ; reads 8MB bitmask (or adj fallback), writes 268MB nt
__global__ __launch_bounds__(256) void k_B(const unsigned long long* __restrict__ bmask,
                                           const float* __restrict__ adj,
                                           const float* __restrict__ s,
                                           const float* __restrict__ denom,
                                           const unsigned int* __restrict__ smaxp,
                                           float* __restrict__ alpha,
                                           int use_mask) {
    const int NSTEP = N_NODES / 256;  // 32 (each wave covers 256 cols/step as float4)
    const int w = threadIdx.x >> 6, lane = threadIdx.x & 63;
    const int row = blockIdx.x * 4 + w;
    const float smax = mono2f(*smaxp);
    const float si = s[row];
    const float mi = lrelu(si + smax);
    const float d = denom[row];
    const float rd = d > 0.f ? 1.f / d : 0.f;
    float* arow = alpha + (size_t)row * N_NODES;
    if (use_mask) {
        const unsigned long long* mrow = bmask + (size_t)row * (N_NODES / 64);
        #pragma unroll 4
        for (int t = 0; t < NSTEP; ++t) {
            int col = t * 256 + lane * 4;
            unsigned long long mb = mrow[t * 4 + (lane >> 4)];
            int sh = (lane & 15) * 4;
            f32x4 sj = *(const f32x4*)&s[col];
            f32x4 o;
            o[0] = ((mb >> (sh + 0)) & 1ull) ? __expf(lrelu(si + sj[0]) - mi) * rd : 0.f;
            o[1] = ((mb >> (sh + 1)) & 1ull) ? __expf(lrelu(si + sj[1]) - mi) * rd : 0.f;
            o[2] = ((mb >> (sh + 2)) & 1ull) ? __expf(lrelu(si + sj[2]) - mi) * rd : 0.f;
            o[3] = ((mb >> (sh + 3)) & 1ull) ? __expf(lrelu(si + sj[3]) - mi) * rd : 0.f;
            __builtin_nontemporal_store(o, (f32x4*)&arow[col]);
        }
    } else {
        const float* adjrow = adj + (size_t)row * N_NODES;
        #pragma unroll 4
        for (int t = 0; t < NSTEP; ++t) {
            int col = t * 256 + lane * 4;
            f32x4 a4 = __builtin_nontemporal_load((const f32x4*)&adjrow[col]);
            f32x4 sj = *(const f32x4*)&s[col];
            f32x4 o;
            o[0] = (a4[0] != 0.f) ? __expf(lrelu(si + sj[0]) - mi) * rd : 0.f;
            o[1] = (a4[1] != 0.f) ? __expf(lrelu(si + sj[1]) - mi) * rd : 0.f;
            o[2] = (a4[2] != 0.f) ? __expf(lrelu(si + sj[2]) - mi) * rd : 0.f;
            o[3] = (a4[3] != 0.f) ? __expf(lrelu(si + sj[3]) - mi) * rd : 0.f;
            __builtin_nontemporal_store(o, (f32x4*)&arow[col]);
        }
    }
}

// z = sigmoid(y/denom)
__global__ __launch_bounds__(256) void k_z(const float* __restrict__ y,
                                           const float* __restrict__ denom,
                                           float* __restrict__ z) {
    int i = blockIdx.x * 256 + threadIdx.x;
    int row = i >> 7;
    float d = denom[row];
    float rd = d > 0.f ? 1.f / d : 0.f;
    float v = y[i] * rd;
    z[i] = 1.f / (1.f + __expf(-v));
}

extern "C" void kernel_launch(void* const* d_in, const int* in_sizes, int n_in,
                              void* d_out, int out_size, void* d_ws, size_t ws_size,
                              hipStream_t stream) {
    const float* h   = (const float*)d_in[0];
    const float* adj = (const float*)d_in[1];
    const float* Ww  = (const float*)d_in[2];
    const float* Wb  = (const float*)d_in[3];
    const float* a   = (const float*)d_in[4];

    float* z     = (float*)d_out;
    float* alpha = z + (size_t)N_NODES * H_DIM;

    char* ws = (char*)d_ws;
    float* y     = (float*)ws;  ws += sizeof(float) * (size_t)N_NODES * H_DIM;   // 4MB (zeroed)
    float* denom = (float*)ws;  ws += sizeof(float) * N_NODES;                   // 32KB (zeroed)
    unsigned int* smax = (unsigned int*)ws;  ws += 256;                          // (zeroed)
    size_t zero_bytes = (size_t)(ws - (char*)d_ws);
    float* Wh    = (float*)ws;  ws += sizeof(float) * (size_t)N_NODES * H_DIM;   // 4MB
    __hip_bfloat16* WhT = (__hip_bfloat16*)ws;
    ws += sizeof(__hip_bfloat16) * (size_t)N_NODES * H_DIM;                      // 2MB
    float* s     = (float*)ws;  ws += sizeof(float) * N_NODES;                   // 32KB
    unsigned long long* bmask = (unsigned long long*)ws;
    size_t base_need  = (size_t)(ws - (char*)d_ws);
    size_t mask_bytes = (size_t)N_NODES * (N_NODES / 64) * sizeof(unsigned long long);
    int use_mask = (ws_size >= base_need + mask_bytes) ? 1 : 0;

    (void)hipMemsetAsync(d_ws, 0, zero_bytes, stream);
    hipLaunchKernelGGL(k_wh, dim3(N_NODES / 32), dim3(256), 0, stream, h, Ww, Wb, Wh, WhT);
    hipLaunchKernelGGL(k_s,  dim3(N_NODES / 4),  dim3(256), 0, stream, Wh, a, s, smax);
    hipLaunchKernelGGL(k_A,  dim3(N_NODES / 64, NKB), dim3(512), 0, stream,
                       adj, WhT, s, smax, denom, y, bmask, use_mask);
    hipLaunchKernelGGL(k_B,  dim3(N_NODES / 4),  dim3(256), 0, stream,
                       bmask, adj, s, denom, smax, alpha, use_mask);
    hipLaunchKernelGGL(k_z,  dim3((N_NODES * H_DIM) / 256), dim3(256), 0, stream,
                       y, denom, z);
}